// Round 1
// baseline (345.386 us; speedup 1.0000x reference)
//
#include <hip/hip_runtime.h>
#include <math.h>

#define D128 128
#define ROWS 4

__device__ __forceinline__ int lower_bound_i(const int* a, int n, int key) {
  int lo = 0, hi = n;
  while (lo < hi) { int mid = (lo + hi) >> 1; if (a[mid] < key) lo = mid + 1; else hi = mid; }
  return lo;
}

// P[M][128] = X[M][128] @ W[128][128], fp32, 128x128 block tile, 8x8/thread
__global__ __launch_bounds__(256) void gemm_128(const float* __restrict__ X,
                                                const float* __restrict__ W,
                                                float* __restrict__ P, int M) {
  __shared__ float At[32][132];  // A chunk, transposed: At[k][row]
  __shared__ float Bs[32][132];  // B chunk: Bs[k][j]
  const int tid = threadIdx.x;
  const int tx = tid & 15;        // col group -> cols tx*8..+7
  const int ty = tid >> 4;        // row group -> rows ty*8..+7
  const int row0 = blockIdx.x * 128;

  float acc[8][8];
#pragma unroll
  for (int i = 0; i < 8; i++)
#pragma unroll
    for (int j = 0; j < 8; j++) acc[i][j] = 0.0f;

  for (int kp = 0; kp < 128; kp += 32) {
    // stage A (transposed): 128 rows x 32 k
#pragma unroll
    for (int it = 0; it < 4; it++) {
      int f = tid + 256 * it;          // 0..1023 float4s
      int r = f >> 3;                  // 0..127
      int kc = (f & 7) * 4;            // 0,4,...,28
      float4 v = make_float4(0.f, 0.f, 0.f, 0.f);
      int gr = row0 + r;
      if (gr < M) v = *(const float4*)(X + (size_t)gr * D128 + kp + kc);
      At[kc + 0][r] = v.x;
      At[kc + 1][r] = v.y;
      At[kc + 2][r] = v.z;
      At[kc + 3][r] = v.w;
    }
    // stage B: 32 k-rows x 128 cols (natural layout)
#pragma unroll
    for (int it = 0; it < 4; it++) {
      int f = tid + 256 * it;
      int kk = f >> 5;                 // 0..31
      int j4 = (f & 31) * 4;
      *(float4*)(&Bs[kk][j4]) = *(const float4*)(W + (size_t)(kp + kk) * D128 + j4);
    }
    __syncthreads();

#pragma unroll 4
    for (int k = 0; k < 32; k++) {
      const float4* pa = (const float4*)(&At[k][ty * 8]);
      const float4* pb = (const float4*)(&Bs[k][tx * 8]);
      float4 a0 = pa[0], a1 = pa[1];
      float4 b0 = pb[0], b1 = pb[1];
      float a[8] = {a0.x, a0.y, a0.z, a0.w, a1.x, a1.y, a1.z, a1.w};
      float b[8] = {b0.x, b0.y, b0.z, b0.w, b1.x, b1.y, b1.z, b1.w};
#pragma unroll
      for (int i = 0; i < 8; i++)
#pragma unroll
        for (int j = 0; j < 8; j++) acc[i][j] = fmaf(a[i], b[j], acc[i][j]);
    }
    __syncthreads();
  }

#pragma unroll
  for (int i = 0; i < 8; i++) {
    int gr = row0 + ty * 8 + i;
    if (gr < M) {
      *(float4*)(P + (size_t)gr * D128 + tx * 8) =
          make_float4(acc[i][0], acc[i][1], acc[i][2], acc[i][3]);
      *(float4*)(P + (size_t)gr * D128 + tx * 8 + 4) =
          make_float4(acc[i][4], acc[i][5], acc[i][6], acc[i][7]);
    }
  }
}

// one wave per edge: raw[e] = tanh(p_src[src]+p_dst[dst]) . w2 * ew[e]
__global__ __launch_bounds__(256) void edge_raw_kernel(
    const float* __restrict__ p_src, const float* __restrict__ p_dst,
    const float* __restrict__ w2, const float* __restrict__ ew,
    const int* __restrict__ src_idx, const int* __restrict__ dst_idx,
    float* __restrict__ raw, int E) {
  const int wave = threadIdx.x >> 6;
  const int lane = threadIdx.x & 63;
  const int e = blockIdx.x * 4 + wave;
  if (e >= E) return;
  const int s = src_idx[e];
  const int d = dst_idx[e];
  float2 ps = *(const float2*)(p_src + (size_t)s * D128 + lane * 2);
  float2 pd = *(const float2*)(p_dst + (size_t)d * D128 + lane * 2);
  float2 w = *(const float2*)(w2 + lane * 2);
  float v = tanhf(ps.x + pd.x) * w.x + tanhf(ps.y + pd.y) * w.y;
#pragma unroll
  for (int off = 32; off >= 1; off >>= 1) v += __shfl_xor(v, off, 64);
  if (lane == 0) raw[e] = v * ew[e];
}

// one 128-thread block per dst node. dst_idx is sorted -> contiguous edge range.
// raw_attn is read as raw scores, then overwritten with normalized attn.
__global__ __launch_bounds__(128) void dst_agg_kernel(
    float* raw_attn, const float* __restrict__ h_src,
    const int* __restrict__ src_idx, const int* __restrict__ dst_idx,
    float* __restrict__ h_global, int E) {
  const int v = blockIdx.x;
  const int t = threadIdx.x;  // d index 0..127
  const int lo = lower_bound_i(dst_idx, E, v);
  const int hi = lower_bound_i(dst_idx, E, v + 1);

  float m = -INFINITY;
  for (int e = lo; e < hi; e++) m = fmaxf(m, raw_attn[e]);

  float den = 0.0f, acc = 0.0f;
  for (int e = lo; e < hi; e++) {
    float ex = expf(raw_attn[e] - m);
    den += ex;
    acc = fmaf(ex, h_src[(size_t)src_idx[e] * D128 + t], acc);
  }
  const float inv = (hi > lo) ? 1.0f / den : 0.0f;
  h_global[(size_t)v * D128 + t] = acc * inv;

  __syncthreads();  // all raw reads done before any attn overwrite
  for (int e = lo + t; e < hi; e += 128) {
    raw_attn[e] = expf(raw_attn[e] - m) * inv;
  }
}

// out = [h_dst|h_global] @ Wo + bo; x = h_dst + out; y = LN(x)*gamma+beta
__global__ __launch_bounds__(128) void out_ln_kernel(
    const float* __restrict__ h_dst, const float* __restrict__ h_global,
    const float* __restrict__ Wo, const float* __restrict__ bo,
    const float* __restrict__ gamma, const float* __restrict__ beta,
    float* __restrict__ y, int N) {
  const int t = threadIdx.x;
  const int v0 = blockIdx.x * ROWS;
  __shared__ float xs[ROWS][260];
  __shared__ float redbuf[ROWS][2][2];

#pragma unroll
  for (int r = 0; r < ROWS; r++) {
    int v = v0 + r;
    float hd = 0.f, hg = 0.f;
    if (v < N) {
      hd = h_dst[(size_t)v * D128 + t];
      hg = h_global[(size_t)v * D128 + t];
    }
    xs[r][t] = hd;
    xs[r][128 + t] = hg;
  }
  __syncthreads();

  float o[ROWS];
#pragma unroll
  for (int r = 0; r < ROWS; r++) o[r] = bo[t];

  for (int k = 0; k < 256; k += 4) {
    float w0 = Wo[(size_t)(k + 0) * D128 + t];
    float w1 = Wo[(size_t)(k + 1) * D128 + t];
    float w2_ = Wo[(size_t)(k + 2) * D128 + t];
    float w3 = Wo[(size_t)(k + 3) * D128 + t];
#pragma unroll
    for (int r = 0; r < ROWS; r++) {
      float4 xv = *(const float4*)(&xs[r][k]);
      o[r] = fmaf(xv.x, w0, o[r]);
      o[r] = fmaf(xv.y, w1, o[r]);
      o[r] = fmaf(xv.z, w2_, o[r]);
      o[r] = fmaf(xv.w, w3, o[r]);
    }
  }

  const int lane = t & 63;
  const int wv = t >> 6;
  float xr[ROWS];
#pragma unroll
  for (int r = 0; r < ROWS; r++) {
    float x = xs[r][t] + o[r];  // residual: h_dst + out
    xr[r] = x;
    float s1 = x, s2 = x * x;
#pragma unroll
    for (int off = 32; off >= 1; off >>= 1) {
      s1 += __shfl_xor(s1, off, 64);
      s2 += __shfl_xor(s2, off, 64);
    }
    if (lane == 0) { redbuf[r][wv][0] = s1; redbuf[r][wv][1] = s2; }
  }
  __syncthreads();

#pragma unroll
  for (int r = 0; r < ROWS; r++) {
    int v = v0 + r;
    if (v >= N) continue;
    float S1 = redbuf[r][0][0] + redbuf[r][1][0];
    float S2 = redbuf[r][0][1] + redbuf[r][1][1];
    float mu = S1 * (1.0f / 128.0f);
    float var = S2 * (1.0f / 128.0f) - mu * mu;
    float out = (xr[r] - mu) / sqrtf(var + 1e-5f) * gamma[t] + beta[t];
    y[(size_t)v * D128 + t] = out;
  }
}

extern "C" void kernel_launch(void* const* d_in, const int* in_sizes, int n_in,
                              void* d_out, int out_size, void* d_ws, size_t ws_size,
                              hipStream_t stream) {
  const float* h_src = (const float*)d_in[0];
  const float* h_dst = (const float*)d_in[1];
  const float* s_emb = (const float*)d_in[2];
  const float* ew    = (const float*)d_in[3];
  const int* src_idx = (const int*)d_in[4];
  const int* dst_idx = (const int*)d_in[5];
  const float* W1    = (const float*)d_in[6];
  const float* w2    = (const float*)d_in[7];
  const float* Wo    = (const float*)d_in[8];
  const float* bo    = (const float*)d_in[9];
  const float* gamma = (const float*)d_in[10];
  const float* beta  = (const float*)d_in[11];

  const int N_src = in_sizes[0] / D128;
  const int N_dst = in_sizes[1] / D128;
  const int E = in_sizes[3];

  float* out_y = (float*)d_out;                       // [N_dst*128]
  float* out_attn = out_y + (size_t)N_dst * D128;     // [E]

  float* p_src = (float*)d_ws;
  float* p_dst = p_src + (size_t)N_src * D128;
  float* h_glob = p_dst + (size_t)N_dst * D128;

  gemm_128<<<(N_src + 127) / 128, 256, 0, stream>>>(h_src, W1, p_src, N_src);
  gemm_128<<<(N_dst + 127) / 128, 256, 0, stream>>>(s_emb, W1 + D128 * D128, p_dst, N_dst);
  edge_raw_kernel<<<(E + 3) / 4, 256, 0, stream>>>(p_src, p_dst, w2, ew, src_idx,
                                                   dst_idx, out_attn, E);
  dst_agg_kernel<<<N_dst, 128, 0, stream>>>(out_attn, h_src, src_idx, dst_idx,
                                            h_glob, E);
  out_ln_kernel<<<(N_dst + ROWS - 1) / ROWS, 128, 0, stream>>>(
      h_dst, h_glob, Wo, bo, gamma, beta, out_y, N_dst);
}

// Round 2
// 333.230 us; speedup vs baseline: 1.0365x; 1.0365x over previous
//
#include <hip/hip_runtime.h>
#include <math.h>

#define D128 128
#define ROWS 4

__device__ __forceinline__ int lower_bound_i(const int* a, int n, int key) {
  int lo = 0, hi = n;
  while (lo < hi) { int mid = (lo + hi) >> 1; if (a[mid] < key) lo = mid + 1; else hi = mid; }
  return lo;
}

// pack two fp32 -> one uint holding 2 bf16 (RNE), elem0 in low 16 bits
__device__ __forceinline__ unsigned int pack_bf2(float x, float y) {
  unsigned int bx = __float_as_uint(x);
  unsigned int by = __float_as_uint(y);
  bx = (bx + 0x7fffu + ((bx >> 16) & 1u)) >> 16;
  by = (by + 0x7fffu + ((by >> 16) & 1u)) & 0xffff0000u;
  return bx | by;
}

__device__ __forceinline__ float bf_lo(unsigned int u) { return __uint_as_float(u << 16); }
__device__ __forceinline__ float bf_hi(unsigned int u) { return __uint_as_float(u & 0xffff0000u); }

// tanh(x) = 1 - 2/(1+exp(2x)); v_exp + v_rcp, exact at +/-inf saturation
__device__ __forceinline__ float fast_tanh(float x) {
  float e = __expf(2.0f * x);
  float r = __builtin_amdgcn_rcpf(1.0f + e);
  return fmaf(-2.0f, r, 1.0f);
}

// P_bf[M][128] (bf16) = X[M][128] @ W[128][128]; optionally emit bf16 copy of X.
// fp32 FMA math, 128x128 block tile, 8x8 per thread.
__global__ __launch_bounds__(256) void gemm_128(const float* __restrict__ X,
                                                const float* __restrict__ W,
                                                unsigned int* __restrict__ P_bf,   // M*64 uints
                                                unsigned int* __restrict__ X_bf,   // M*64 uints or null
                                                int M) {
  __shared__ float At[32][132];
  __shared__ float Bs[32][132];
  const int tid = threadIdx.x;
  const int tx = tid & 15;
  const int ty = tid >> 4;
  const int row0 = blockIdx.x * 128;

  float acc[8][8];
#pragma unroll
  for (int i = 0; i < 8; i++)
#pragma unroll
    for (int j = 0; j < 8; j++) acc[i][j] = 0.0f;

  for (int kp = 0; kp < 128; kp += 32) {
#pragma unroll
    for (int it = 0; it < 4; it++) {
      int f = tid + 256 * it;
      int r = f >> 3;
      int kc = (f & 7) * 4;
      float4 v = make_float4(0.f, 0.f, 0.f, 0.f);
      int gr = row0 + r;
      if (gr < M) v = *(const float4*)(X + (size_t)gr * D128 + kp + kc);
      At[kc + 0][r] = v.x;
      At[kc + 1][r] = v.y;
      At[kc + 2][r] = v.z;
      At[kc + 3][r] = v.w;
      if (X_bf && gr < M) {
        uint2 p;
        p.x = pack_bf2(v.x, v.y);
        p.y = pack_bf2(v.z, v.w);
        *(uint2*)(X_bf + (size_t)gr * 64 + (kp + kc) / 2) = p;
      }
    }
#pragma unroll
    for (int it = 0; it < 4; it++) {
      int f = tid + 256 * it;
      int kk = f >> 5;
      int j4 = (f & 31) * 4;
      *(float4*)(&Bs[kk][j4]) = *(const float4*)(W + (size_t)(kp + kk) * D128 + j4);
    }
    __syncthreads();

#pragma unroll 4
    for (int k = 0; k < 32; k++) {
      const float4* pa = (const float4*)(&At[k][ty * 8]);
      const float4* pb = (const float4*)(&Bs[k][tx * 8]);
      float4 a0 = pa[0], a1 = pa[1];
      float4 b0 = pb[0], b1 = pb[1];
      float a[8] = {a0.x, a0.y, a0.z, a0.w, a1.x, a1.y, a1.z, a1.w};
      float b[8] = {b0.x, b0.y, b0.z, b0.w, b1.x, b1.y, b1.z, b1.w};
#pragma unroll
      for (int i = 0; i < 8; i++)
#pragma unroll
        for (int j = 0; j < 8; j++) acc[i][j] = fmaf(a[i], b[j], acc[i][j]);
    }
    __syncthreads();
  }

#pragma unroll
  for (int i = 0; i < 8; i++) {
    int gr = row0 + ty * 8 + i;
    if (gr < M) {
      uint4 p;
      p.x = pack_bf2(acc[i][0], acc[i][1]);
      p.y = pack_bf2(acc[i][2], acc[i][3]);
      p.z = pack_bf2(acc[i][4], acc[i][5]);
      p.w = pack_bf2(acc[i][6], acc[i][7]);
      *(uint4*)(P_bf + (size_t)gr * 64 + tx * 4) = p;
    }
  }
}

// one wave per edge: raw[e] = tanh(p_src[src]+p_dst[dst]) . w2 * ew[e]
// p rows are bf16 (uint = 2 channels per lane)
__global__ __launch_bounds__(256) void edge_raw_kernel(
    const unsigned int* __restrict__ p_src_bf, const unsigned int* __restrict__ p_dst_bf,
    const float* __restrict__ w2, const float* __restrict__ ew,
    const int* __restrict__ src_idx, const int* __restrict__ dst_idx,
    float* __restrict__ raw, int E) {
  const int wave = threadIdx.x >> 6;
  const int lane = threadIdx.x & 63;
  const int e = blockIdx.x * 4 + wave;
  if (e >= E) return;
  const int s = src_idx[e];
  const int d = dst_idx[e];
  unsigned int us = p_src_bf[(size_t)s * 64 + lane];
  unsigned int ud = p_dst_bf[(size_t)d * 64 + lane];
  float2 w = *(const float2*)(w2 + lane * 2);
  float v = fast_tanh(bf_lo(us) + bf_lo(ud)) * w.x +
            fast_tanh(bf_hi(us) + bf_hi(ud)) * w.y;
#pragma unroll
  for (int off = 32; off >= 1; off >>= 1) v += __shfl_xor(v, off, 64);
  if (lane == 0) raw[e] = v * ew[e];
}

// one 128-thread block per dst node; dst_idx sorted -> contiguous edge range.
// h_src gathered as bf16. raw_attn read, then overwritten with normalized attn.
__global__ __launch_bounds__(128) void dst_agg_kernel(
    float* raw_attn, const unsigned short* __restrict__ h_src_bf,
    const int* __restrict__ src_idx, const int* __restrict__ dst_idx,
    float* __restrict__ h_global, int E) {
  const int v = blockIdx.x;
  const int t = threadIdx.x;
  const int lo = lower_bound_i(dst_idx, E, v);
  const int hi = lower_bound_i(dst_idx, E, v + 1);

  float m = -INFINITY;
  for (int e = lo; e < hi; e++) m = fmaxf(m, raw_attn[e]);

  float den = 0.0f, acc0 = 0.0f, acc1 = 0.0f;
  int e = lo;
  for (; e + 1 < hi; e += 2) {
    float r0 = raw_attn[e], r1 = raw_attn[e + 1];
    int s0 = src_idx[e], s1 = src_idx[e + 1];
    float x0 = __uint_as_float((unsigned int)h_src_bf[(size_t)s0 * D128 + t] << 16);
    float x1 = __uint_as_float((unsigned int)h_src_bf[(size_t)s1 * D128 + t] << 16);
    float ex0 = __expf(r0 - m);
    float ex1 = __expf(r1 - m);
    den += ex0 + ex1;
    acc0 = fmaf(ex0, x0, acc0);
    acc1 = fmaf(ex1, x1, acc1);
  }
  if (e < hi) {
    float ex = __expf(raw_attn[e] - m);
    float x = __uint_as_float((unsigned int)h_src_bf[(size_t)src_idx[e] * D128 + t] << 16);
    den += ex;
    acc0 = fmaf(ex, x, acc0);
  }
  const float inv = (hi > lo) ? 1.0f / den : 0.0f;
  h_global[(size_t)v * D128 + t] = (acc0 + acc1) * inv;

  __syncthreads();  // all raw reads done before any attn overwrite
  for (int e2 = lo + t; e2 < hi; e2 += 128) {
    raw_attn[e2] = __expf(raw_attn[e2] - m) * inv;
  }
}

// out = [h_dst|h_global] @ Wo + bo; x = h_dst + out; y = LN(x)*gamma+beta
__global__ __launch_bounds__(128) void out_ln_kernel(
    const float* __restrict__ h_dst, const float* __restrict__ h_global,
    const float* __restrict__ Wo, const float* __restrict__ bo,
    const float* __restrict__ gamma, const float* __restrict__ beta,
    float* __restrict__ y, int N) {
  const int t = threadIdx.x;
  const int v0 = blockIdx.x * ROWS;
  __shared__ float xs[ROWS][260];
  __shared__ float redbuf[ROWS][2][2];

#pragma unroll
  for (int r = 0; r < ROWS; r++) {
    int v = v0 + r;
    float hd = 0.f, hg = 0.f;
    if (v < N) {
      hd = h_dst[(size_t)v * D128 + t];
      hg = h_global[(size_t)v * D128 + t];
    }
    xs[r][t] = hd;
    xs[r][128 + t] = hg;
  }
  __syncthreads();

  float o[ROWS];
#pragma unroll
  for (int r = 0; r < ROWS; r++) o[r] = bo[t];

  for (int k = 0; k < 256; k += 4) {
    float w0 = Wo[(size_t)(k + 0) * D128 + t];
    float w1 = Wo[(size_t)(k + 1) * D128 + t];
    float w2_ = Wo[(size_t)(k + 2) * D128 + t];
    float w3 = Wo[(size_t)(k + 3) * D128 + t];
#pragma unroll
    for (int r = 0; r < ROWS; r++) {
      float4 xv = *(const float4*)(&xs[r][k]);
      o[r] = fmaf(xv.x, w0, o[r]);
      o[r] = fmaf(xv.y, w1, o[r]);
      o[r] = fmaf(xv.z, w2_, o[r]);
      o[r] = fmaf(xv.w, w3, o[r]);
    }
  }

  const int lane = t & 63;
  const int wv = t >> 6;
  float xr[ROWS];
#pragma unroll
  for (int r = 0; r < ROWS; r++) {
    float x = xs[r][t] + o[r];
    xr[r] = x;
    float s1 = x, s2 = x * x;
#pragma unroll
    for (int off = 32; off >= 1; off >>= 1) {
      s1 += __shfl_xor(s1, off, 64);
      s2 += __shfl_xor(s2, off, 64);
    }
    if (lane == 0) { redbuf[r][wv][0] = s1; redbuf[r][wv][1] = s2; }
  }
  __syncthreads();

#pragma unroll
  for (int r = 0; r < ROWS; r++) {
    int v = v0 + r;
    if (v >= N) continue;
    float S1 = redbuf[r][0][0] + redbuf[r][1][0];
    float S2 = redbuf[r][0][1] + redbuf[r][1][1];
    float mu = S1 * (1.0f / 128.0f);
    float var = S2 * (1.0f / 128.0f) - mu * mu;
    float out = (xr[r] - mu) / sqrtf(var + 1e-5f) * gamma[t] + beta[t];
    y[(size_t)v * D128 + t] = out;
  }
}

extern "C" void kernel_launch(void* const* d_in, const int* in_sizes, int n_in,
                              void* d_out, int out_size, void* d_ws, size_t ws_size,
                              hipStream_t stream) {
  const float* h_src = (const float*)d_in[0];
  const float* h_dst = (const float*)d_in[1];
  const float* s_emb = (const float*)d_in[2];
  const float* ew    = (const float*)d_in[3];
  const int* src_idx = (const int*)d_in[4];
  const int* dst_idx = (const int*)d_in[5];
  const float* W1    = (const float*)d_in[6];
  const float* w2    = (const float*)d_in[7];
  const float* Wo    = (const float*)d_in[8];
  const float* bo    = (const float*)d_in[9];
  const float* gamma = (const float*)d_in[10];
  const float* beta  = (const float*)d_in[11];

  const int N_src = in_sizes[0] / D128;
  const int N_dst = in_sizes[1] / D128;
  const int E = in_sizes[3];

  float* out_y = (float*)d_out;                       // [N_dst*128]
  float* out_attn = out_y + (size_t)N_dst * D128;     // [E]

  // ws layout (uints are 2 bf16 each):
  unsigned int* p_src_bf = (unsigned int*)d_ws;                 // N_src*64
  unsigned int* p_dst_bf = p_src_bf + (size_t)N_src * 64;       // N_dst*64
  unsigned int* h_src_bf = p_dst_bf + (size_t)N_dst * 64;       // N_src*64
  float* h_glob = (float*)(h_src_bf + (size_t)N_src * 64);      // N_dst*128

  gemm_128<<<(N_src + 127) / 128, 256, 0, stream>>>(h_src, W1, p_src_bf, h_src_bf, N_src);
  gemm_128<<<(N_dst + 127) / 128, 256, 0, stream>>>(s_emb, W1 + D128 * D128, p_dst_bf,
                                                    (unsigned int*)nullptr, N_dst);
  edge_raw_kernel<<<(E + 3) / 4, 256, 0, stream>>>(p_src_bf, p_dst_bf, w2, ew, src_idx,
                                                   dst_idx, out_attn, E);
  dst_agg_kernel<<<N_dst, 128, 0, stream>>>(out_attn, (const unsigned short*)h_src_bf,
                                            src_idx, dst_idx, h_glob, E);
  out_ln_kernel<<<(N_dst + ROWS - 1) / ROWS, 128, 0, stream>>>(
      h_dst, h_glob, Wo, bo, gamma, beta, out_y, N_dst);
}

// Round 3
// 284.045 us; speedup vs baseline: 1.2160x; 1.1732x over previous
//
#include <hip/hip_runtime.h>
#include <math.h>

#define D128 128
#define ROWS 4

typedef unsigned int uint32;
typedef unsigned short ushort16;
typedef short bf16x8 __attribute__((ext_vector_type(8)));
typedef float f32x4 __attribute__((ext_vector_type(4)));

__device__ __forceinline__ int lower_bound_i(const int* a, int n, int key) {
  int lo = 0, hi = n;
  while (lo < hi) { int mid = (lo + hi) >> 1; if (a[mid] < key) lo = mid + 1; else hi = mid; }
  return lo;
}

// fp32 -> bf16 (RNE)
__device__ __forceinline__ unsigned short bf16_of(float x) {
  uint32 u = __float_as_uint(x);
  return (unsigned short)((u + 0x7fffu + ((u >> 16) & 1u)) >> 16);
}
// pack two fp32 -> uint (elem0 in low 16)
__device__ __forceinline__ uint32 pack_bf2(float x, float y) {
  uint32 bx = __float_as_uint(x);
  uint32 by = __float_as_uint(y);
  bx = (bx + 0x7fffu + ((bx >> 16) & 1u)) >> 16;
  by = (by + 0x7fffu + ((by >> 16) & 1u)) & 0xffff0000u;
  return bx | by;
}
__device__ __forceinline__ float bf_lo(uint32 u) { return __uint_as_float(u << 16); }
__device__ __forceinline__ float bf_hi(uint32 u) { return __uint_as_float(u & 0xffff0000u); }

// tanh(x) = 1 - 2/(1+exp(2x)) via v_exp + v_rcp
__device__ __forceinline__ float fast_tanh(float x) {
  float e = __expf(2.0f * x);
  float r = __builtin_amdgcn_rcpf(1.0f + e);
  return fmaf(-2.0f, r, 1.0f);
}

// ---------------------------------------------------------------------------
// P_bf[M][128] (bf16) = X[M][128] @ W[128][128] via MFMA 16x16x32 bf16.
// Optionally emits bf16 copy of X (X_bf). 256 threads, 64-row tile.
// Wt staged transposed in LDS so B-frags are contiguous ds_read_b128.
// ---------------------------------------------------------------------------
__global__ __launch_bounds__(256) void gemm_mfma(const float* __restrict__ X,
                                                 const float* __restrict__ W,
                                                 unsigned short* __restrict__ P_bf,
                                                 uint32* __restrict__ X_bf,  // or null
                                                 int M) {
  __shared__ unsigned short Xs[64][136];   // row stride 272B (16B aligned)
  __shared__ unsigned short Wt[128][136];  // Wt[n][k]
  const int tid = threadIdx.x;
  const int row0 = blockIdx.x * 64;

  // stage W transposed: W[k][n] fp32 -> Wt[n][k] bf16
#pragma unroll
  for (int it = 0; it < 16; it++) {
    int f = tid + 256 * it;          // 0..4095
    int k = f >> 5;
    int n4 = (f & 31) * 4;
    float4 v = *(const float4*)(W + (size_t)k * D128 + n4);
    Wt[n4 + 0][k] = bf16_of(v.x);
    Wt[n4 + 1][k] = bf16_of(v.y);
    Wt[n4 + 2][k] = bf16_of(v.z);
    Wt[n4 + 3][k] = bf16_of(v.w);
  }
  // stage X tile: fp32 -> bf16, row-major; optional global bf16 copy
#pragma unroll
  for (int it = 0; it < 8; it++) {
    int f = tid + 256 * it;          // 0..2047
    int r = f >> 5;
    int c4 = (f & 31) * 4;
    int gr = row0 + r;
    float4 v = make_float4(0.f, 0.f, 0.f, 0.f);
    if (gr < M) v = *(const float4*)(X + (size_t)gr * D128 + c4);
    uint2 p;
    p.x = pack_bf2(v.x, v.y);
    p.y = pack_bf2(v.z, v.w);
    *(uint2*)(&Xs[r][c4]) = p;
    if (X_bf && gr < M) *(uint2*)(X_bf + (size_t)gr * 64 + (c4 >> 1)) = p;
  }
  __syncthreads();

  const int wave = tid >> 6;
  const int lane = tid & 63;
  const int m = lane & 15;
  const int quad = lane >> 4;

  f32x4 acc[8];
#pragma unroll
  for (int nt = 0; nt < 8; nt++) acc[nt] = (f32x4){0.f, 0.f, 0.f, 0.f};

#pragma unroll
  for (int kc = 0; kc < 4; kc++) {
    bf16x8 a = *(const bf16x8*)(&Xs[wave * 16 + m][kc * 32 + quad * 8]);
#pragma unroll
    for (int nt = 0; nt < 8; nt++) {
      bf16x8 b = *(const bf16x8*)(&Wt[nt * 16 + m][kc * 32 + quad * 8]);
      acc[nt] = __builtin_amdgcn_mfma_f32_16x16x32_bf16(a, b, acc[nt], 0, 0, 0);
    }
  }

  // C/D: col = lane&15, row = quad*4 + reg
#pragma unroll
  for (int nt = 0; nt < 8; nt++) {
#pragma unroll
    for (int r = 0; r < 4; r++) {
      int grow = row0 + wave * 16 + quad * 4 + r;
      if (grow < M) P_bf[(size_t)grow * D128 + nt * 16 + m] = bf16_of(acc[nt][r]);
    }
  }
}

// ---------------------------------------------------------------------------
// one THREAD per edge: raw[e] = tanh(p_src[src]+p_dst[dst]) . w2 * ew[e]
// per-lane serial dot over 128 channels -> no cross-lane reduction.
// ---------------------------------------------------------------------------
__global__ __launch_bounds__(256) void edge_raw_kernel(
    const uint32* __restrict__ p_src_bf, const uint32* __restrict__ p_dst_bf,
    const float* __restrict__ w2, const float* __restrict__ ew,
    const int* __restrict__ src_idx, const int* __restrict__ dst_idx,
    float* __restrict__ raw, int E) {
  __shared__ float sw2[128];
  const int tid = threadIdx.x;
  if (tid < 128) sw2[tid] = w2[tid];
  __syncthreads();
  const int e = blockIdx.x * 256 + tid;
  if (e >= E) return;
  const uint4* ps = (const uint4*)(p_src_bf + (size_t)src_idx[e] * 64);
  const uint4* pd = (const uint4*)(p_dst_bf + (size_t)dst_idx[e] * 64);
  float acc = 0.0f;
#pragma unroll 4
  for (int k8 = 0; k8 < 16; k8++) {     // 8 channels per iter
    uint4 us = ps[k8];
    uint4 ud = pd[k8];
    float4 wA = *(const float4*)(&sw2[k8 * 8]);
    float4 wB = *(const float4*)(&sw2[k8 * 8 + 4]);
    acc = fmaf(fast_tanh(bf_lo(us.x) + bf_lo(ud.x)), wA.x, acc);
    acc = fmaf(fast_tanh(bf_hi(us.x) + bf_hi(ud.x)), wA.y, acc);
    acc = fmaf(fast_tanh(bf_lo(us.y) + bf_lo(ud.y)), wA.z, acc);
    acc = fmaf(fast_tanh(bf_hi(us.y) + bf_hi(ud.y)), wA.w, acc);
    acc = fmaf(fast_tanh(bf_lo(us.z) + bf_lo(ud.z)), wB.x, acc);
    acc = fmaf(fast_tanh(bf_hi(us.z) + bf_hi(ud.z)), wB.y, acc);
    acc = fmaf(fast_tanh(bf_lo(us.w) + bf_lo(ud.w)), wB.z, acc);
    acc = fmaf(fast_tanh(bf_hi(us.w) + bf_hi(ud.w)), wB.w, acc);
  }
  raw[e] = acc * ew[e];
}

// ---------------------------------------------------------------------------
// one 256-thread block per dst; dst_idx sorted -> contiguous edge range.
// 2 edge-groups in parallel (g = tid>>7), parallel max phase.
// ---------------------------------------------------------------------------
__global__ __launch_bounds__(256) void dst_agg_kernel(
    float* raw_attn, const ushort16* __restrict__ h_src_bf,
    const int* __restrict__ src_idx, const int* __restrict__ dst_idx,
    float* __restrict__ h_global, int E) {
  const int v = blockIdx.x;
  const int tid = threadIdx.x;
  const int t = tid & 127;   // channel
  const int g = tid >> 7;    // edge group
  const int lo = lower_bound_i(dst_idx, E, v);
  const int hi = lower_bound_i(dst_idx, E, v + 1);

  __shared__ float wmax[4];
  __shared__ float sacc[2][128];
  __shared__ float sden[2];

  // parallel max
  float lm = -INFINITY;
  for (int e = lo + tid; e < hi; e += 256) lm = fmaxf(lm, raw_attn[e]);
#pragma unroll
  for (int off = 32; off >= 1; off >>= 1) lm = fmaxf(lm, __shfl_xor(lm, off, 64));
  if ((tid & 63) == 0) wmax[tid >> 6] = lm;
  __syncthreads();
  const float m = fmaxf(fmaxf(wmax[0], wmax[1]), fmaxf(wmax[2], wmax[3]));

  // main gather loop, 2 groups
  float den = 0.0f, acc = 0.0f;
  for (int e = lo + g; e < hi; e += 2) {
    float ex = __expf(raw_attn[e] - m);
    int s = src_idx[e];
    float x = __uint_as_float((uint32)h_src_bf[(size_t)s * D128 + t] << 16);
    den += ex;
    acc = fmaf(ex, x, acc);
  }
  sacc[g][t] = acc;
  if (t == 0) sden[g] = den;
  __syncthreads();

  const float dtot = sden[0] + sden[1];
  const float inv = (hi > lo) ? 1.0f / dtot : 0.0f;
  if (g == 0) h_global[(size_t)v * D128 + t] = (sacc[0][t] + sacc[1][t]) * inv;

  // normalized attn (each e touched exactly once; all raw reads above done)
  for (int e = lo + tid; e < hi; e += 256) {
    raw_attn[e] = __expf(raw_attn[e] - m) * inv;
  }
}

// ---------------------------------------------------------------------------
// out = [h_dst|h_global] @ Wo + bo; x = h_dst + out; y = LN(x)*gamma+beta
// ---------------------------------------------------------------------------
__global__ __launch_bounds__(128) void out_ln_kernel(
    const float* __restrict__ h_dst, const float* __restrict__ h_global,
    const float* __restrict__ Wo, const float* __restrict__ bo,
    const float* __restrict__ gamma, const float* __restrict__ beta,
    float* __restrict__ y, int N) {
  const int t = threadIdx.x;
  const int v0 = blockIdx.x * ROWS;
  __shared__ float xs[ROWS][260];
  __shared__ float redbuf[ROWS][2][2];

#pragma unroll
  for (int r = 0; r < ROWS; r++) {
    int v = v0 + r;
    float hd = 0.f, hg = 0.f;
    if (v < N) {
      hd = h_dst[(size_t)v * D128 + t];
      hg = h_global[(size_t)v * D128 + t];
    }
    xs[r][t] = hd;
    xs[r][128 + t] = hg;
  }
  __syncthreads();

  float o[ROWS];
#pragma unroll
  for (int r = 0; r < ROWS; r++) o[r] = bo[t];

  for (int k = 0; k < 256; k += 4) {
    float w0 = Wo[(size_t)(k + 0) * D128 + t];
    float w1 = Wo[(size_t)(k + 1) * D128 + t];
    float w2_ = Wo[(size_t)(k + 2) * D128 + t];
    float w3 = Wo[(size_t)(k + 3) * D128 + t];
#pragma unroll
    for (int r = 0; r < ROWS; r++) {
      float4 xv = *(const float4*)(&xs[r][k]);
      o[r] = fmaf(xv.x, w0, o[r]);
      o[r] = fmaf(xv.y, w1, o[r]);
      o[r] = fmaf(xv.z, w2_, o[r]);
      o[r] = fmaf(xv.w, w3, o[r]);
    }
  }

  const int lane = t & 63;
  const int wv = t >> 6;
  float xr[ROWS];
#pragma unroll
  for (int r = 0; r < ROWS; r++) {
    float x = xs[r][t] + o[r];
    xr[r] = x;
    float s1 = x, s2 = x * x;
#pragma unroll
    for (int off = 32; off >= 1; off >>= 1) {
      s1 += __shfl_xor(s1, off, 64);
      s2 += __shfl_xor(s2, off, 64);
    }
    if (lane == 0) { redbuf[r][wv][0] = s1; redbuf[r][wv][1] = s2; }
  }
  __syncthreads();

#pragma unroll
  for (int r = 0; r < ROWS; r++) {
    int v = v0 + r;
    if (v >= N) continue;
    float S1 = redbuf[r][0][0] + redbuf[r][1][0];
    float S2 = redbuf[r][0][1] + redbuf[r][1][1];
    float mu = S1 * (1.0f / 128.0f);
    float var = S2 * (1.0f / 128.0f) - mu * mu;
    float out = (xr[r] - mu) / sqrtf(var + 1e-5f) * gamma[t] + beta[t];
    y[(size_t)v * D128 + t] = out;
  }
}

extern "C" void kernel_launch(void* const* d_in, const int* in_sizes, int n_in,
                              void* d_out, int out_size, void* d_ws, size_t ws_size,
                              hipStream_t stream) {
  const float* h_src = (const float*)d_in[0];
  const float* h_dst = (const float*)d_in[1];
  const float* s_emb = (const float*)d_in[2];
  const float* ew    = (const float*)d_in[3];
  const int* src_idx = (const int*)d_in[4];
  const int* dst_idx = (const int*)d_in[5];
  const float* W1    = (const float*)d_in[6];
  const float* w2    = (const float*)d_in[7];
  const float* Wo    = (const float*)d_in[8];
  const float* bo    = (const float*)d_in[9];
  const float* gamma = (const float*)d_in[10];
  const float* beta  = (const float*)d_in[11];

  const int N_src = in_sizes[0] / D128;
  const int N_dst = in_sizes[1] / D128;
  const int E = in_sizes[3];

  float* out_y = (float*)d_out;                       // [N_dst*128]
  float* out_attn = out_y + (size_t)N_dst * D128;     // [E]

  // ws layout (uints are 2 bf16 each):
  uint32* p_src_bf = (uint32*)d_ws;                         // N_src*64
  uint32* p_dst_bf = p_src_bf + (size_t)N_src * 64;         // N_dst*64
  uint32* h_src_bf = p_dst_bf + (size_t)N_dst * 64;         // N_src*64
  float* h_glob = (float*)(h_src_bf + (size_t)N_src * 64);  // N_dst*128

  gemm_mfma<<<(N_src + 63) / 64, 256, 0, stream>>>(
      h_src, W1, (unsigned short*)p_src_bf, h_src_bf, N_src);
  gemm_mfma<<<(N_dst + 63) / 64, 256, 0, stream>>>(
      s_emb, W1 + D128 * D128, (unsigned short*)p_dst_bf, (uint32*)nullptr, N_dst);
  edge_raw_kernel<<<(E + 255) / 256, 256, 0, stream>>>(p_src_bf, p_dst_bf, w2, ew,
                                                       src_idx, dst_idx, out_attn, E);
  dst_agg_kernel<<<N_dst, 256, 0, stream>>>(out_attn, (const ushort16*)h_src_bf,
                                            src_idx, dst_idx, h_glob, E);
  out_ln_kernel<<<(N_dst + ROWS - 1) / ROWS, 128, 0, stream>>>(
      h_dst, h_glob, Wo, bo, gamma, beta, out_y, N_dst);
}

// Round 4
// 221.994 us; speedup vs baseline: 1.5558x; 1.2795x over previous
//
#include <hip/hip_runtime.h>
#include <math.h>

#define D128 128
#define ROWS 4

typedef unsigned int uint32;
typedef short bf16x8 __attribute__((ext_vector_type(8)));
typedef float f32x4 __attribute__((ext_vector_type(4)));

// fp32 -> bf16 (RNE)
__device__ __forceinline__ unsigned short bf16_of(float x) {
  uint32 u = __float_as_uint(x);
  return (unsigned short)((u + 0x7fffu + ((u >> 16) & 1u)) >> 16);
}
__device__ __forceinline__ uint32 pack_bf2(float x, float y) {
  uint32 bx = __float_as_uint(x);
  uint32 by = __float_as_uint(y);
  bx = (bx + 0x7fffu + ((bx >> 16) & 1u)) >> 16;
  by = (by + 0x7fffu + ((by >> 16) & 1u)) & 0xffff0000u;
  return bx | by;
}
__device__ __forceinline__ float bf_lo(uint32 u) { return __uint_as_float(u << 16); }
__device__ __forceinline__ float bf_hi(uint32 u) { return __uint_as_float(u & 0xffff0000u); }

// tanh(x) = 1 - 2/(1+exp(2x)) via v_exp + v_rcp
__device__ __forceinline__ float fast_tanh(float x) {
  float e = __expf(2.0f * x);
  float r = __builtin_amdgcn_rcpf(1.0f + e);
  return fmaf(-2.0f, r, 1.0f);
}

// ---------------------------------------------------------------------------
// seg_offsets: dst_idx sorted -> off[v] = first edge with dst >= v, off[N]=E.
// ---------------------------------------------------------------------------
__global__ __launch_bounds__(256) void seg_offsets_kernel(
    const int* __restrict__ dst_idx, int* __restrict__ off, int E, int N) {
  int e = blockIdx.x * 256 + threadIdx.x;
  if (e >= E) return;
  int d = dst_idx[e];
  int dprev = (e == 0) ? -1 : dst_idx[e - 1];
  for (int v = dprev + 1; v <= d; v++) off[v] = e;
  if (e == E - 1) {
    for (int v = d + 1; v <= N; v++) off[v] = E;
  }
}

// ---------------------------------------------------------------------------
// P_bf[M][128] (bf16) = X[M][128] @ W[128][128] via MFMA 16x16x32 bf16.
// Optionally emits bf16 copy of X. 256 threads, 64-row tile.
// ---------------------------------------------------------------------------
__global__ __launch_bounds__(256) void gemm_mfma(const float* __restrict__ X,
                                                 const float* __restrict__ W,
                                                 unsigned short* __restrict__ P_bf,
                                                 uint32* __restrict__ X_bf,  // or null
                                                 int M) {
  __shared__ unsigned short Xs[64][136];
  __shared__ unsigned short Wt[128][136];  // Wt[n][k]
  const int tid = threadIdx.x;
  const int row0 = blockIdx.x * 64;

#pragma unroll
  for (int it = 0; it < 16; it++) {
    int f = tid + 256 * it;
    int k = f >> 5;
    int n4 = (f & 31) * 4;
    float4 v = *(const float4*)(W + (size_t)k * D128 + n4);
    Wt[n4 + 0][k] = bf16_of(v.x);
    Wt[n4 + 1][k] = bf16_of(v.y);
    Wt[n4 + 2][k] = bf16_of(v.z);
    Wt[n4 + 3][k] = bf16_of(v.w);
  }
#pragma unroll
  for (int it = 0; it < 8; it++) {
    int f = tid + 256 * it;
    int r = f >> 5;
    int c4 = (f & 31) * 4;
    int gr = row0 + r;
    float4 v = make_float4(0.f, 0.f, 0.f, 0.f);
    if (gr < M) v = *(const float4*)(X + (size_t)gr * D128 + c4);
    uint2 p;
    p.x = pack_bf2(v.x, v.y);
    p.y = pack_bf2(v.z, v.w);
    *(uint2*)(&Xs[r][c4]) = p;
    if (X_bf && gr < M) *(uint2*)(X_bf + (size_t)gr * 64 + (c4 >> 1)) = p;
  }
  __syncthreads();

  const int wave = tid >> 6;
  const int lane = tid & 63;
  const int m = lane & 15;
  const int quad = lane >> 4;

  f32x4 acc[8];
#pragma unroll
  for (int nt = 0; nt < 8; nt++) acc[nt] = (f32x4){0.f, 0.f, 0.f, 0.f};

#pragma unroll
  for (int kc = 0; kc < 4; kc++) {
    bf16x8 a = *(const bf16x8*)(&Xs[wave * 16 + m][kc * 32 + quad * 8]);
#pragma unroll
    for (int nt = 0; nt < 8; nt++) {
      bf16x8 b = *(const bf16x8*)(&Wt[nt * 16 + m][kc * 32 + quad * 8]);
      acc[nt] = __builtin_amdgcn_mfma_f32_16x16x32_bf16(a, b, acc[nt], 0, 0, 0);
    }
  }

  // C/D: col = lane&15, row = quad*4 + reg
#pragma unroll
  for (int nt = 0; nt < 8; nt++) {
#pragma unroll
    for (int r = 0; r < 4; r++) {
      int grow = row0 + wave * 16 + quad * 4 + r;
      if (grow < M) P_bf[(size_t)grow * D128 + nt * 16 + m] = bf16_of(acc[nt][r]);
    }
  }
}

// ---------------------------------------------------------------------------
// 16 lanes per edge: raw[e] = tanh(p_src[src]+p_dst[dst]) . w2 * ew[e]
// lane covers 8 channels (one 16B load per row), width-16 shuffle reduce.
// ---------------------------------------------------------------------------
__global__ __launch_bounds__(256) void edge_raw_kernel(
    const uint32* __restrict__ p_src_bf, const uint32* __restrict__ p_dst_bf,
    const float* __restrict__ w2, const float* __restrict__ ew,
    const int* __restrict__ src_idx, const int* __restrict__ dst_idx,
    float* __restrict__ raw, int E) {
  __shared__ float sw2[128];
  const int tid = threadIdx.x;
  if (tid < 128) sw2[tid] = w2[tid];
  __syncthreads();
  const int sub = tid & 15;   // lane within edge -> channels sub*8..+7
  const int e = blockIdx.x * 16 + (tid >> 4);
  if (e >= E) return;
  const int s = src_idx[e];
  const int d = dst_idx[e];
  uint4 us = *(const uint4*)(p_src_bf + (size_t)s * 64 + sub * 4);
  uint4 ud = *(const uint4*)(p_dst_bf + (size_t)d * 64 + sub * 4);
  float4 wA = *(const float4*)(&sw2[sub * 8]);
  float4 wB = *(const float4*)(&sw2[sub * 8 + 4]);
  float acc;
  acc = fast_tanh(bf_lo(us.x) + bf_lo(ud.x)) * wA.x;
  acc = fmaf(fast_tanh(bf_hi(us.x) + bf_hi(ud.x)), wA.y, acc);
  acc = fmaf(fast_tanh(bf_lo(us.y) + bf_lo(ud.y)), wA.z, acc);
  acc = fmaf(fast_tanh(bf_hi(us.y) + bf_hi(ud.y)), wA.w, acc);
  acc = fmaf(fast_tanh(bf_lo(us.z) + bf_lo(ud.z)), wB.x, acc);
  acc = fmaf(fast_tanh(bf_hi(us.z) + bf_hi(ud.z)), wB.y, acc);
  acc = fmaf(fast_tanh(bf_lo(us.w) + bf_lo(ud.w)), wB.z, acc);
  acc = fmaf(fast_tanh(bf_hi(us.w) + bf_hi(ud.w)), wB.w, acc);
#pragma unroll
  for (int o = 1; o <= 8; o <<= 1) acc += __shfl_xor(acc, o, 64);
  if (sub == 0) raw[e] = acc * ew[e];
}

// ---------------------------------------------------------------------------
// one 128-thread block (2 waves) per dst. off[] gives edge range (no search).
// pass1 max, pass2 den, pass3 chunked gather with 8 outstanding row loads
// per wave; attn written normalized during pass3. Lane covers 2 channels.
// ---------------------------------------------------------------------------
__global__ __launch_bounds__(128) void dst_agg_kernel(
    float* raw_attn, const uint32* __restrict__ h_src_bf2,
    const int* __restrict__ src_idx, const int* __restrict__ off,
    float* __restrict__ h_global) {
  const int v = blockIdx.x;
  const int tid = threadIdx.x;
  const int t2 = tid & 63;   // channel pair
  const int g = tid >> 6;    // wave id
  const int lo = off[v], hi = off[v + 1];
  const int deg = hi - lo;

  __shared__ float sred[2];
  __shared__ float sex[128];
  __shared__ int ssrc[128];
  __shared__ float sacc[64][2];

  // pass 1: max
  float lm = -INFINITY;
  for (int e = lo + tid; e < hi; e += 128) lm = fmaxf(lm, raw_attn[e]);
#pragma unroll
  for (int o = 32; o >= 1; o >>= 1) lm = fmaxf(lm, __shfl_xor(lm, o, 64));
  if (t2 == 0) sred[g] = lm;
  __syncthreads();
  const float m = fmaxf(sred[0], sred[1]);
  __syncthreads();

  // pass 2: den
  float dp = 0.f;
  for (int e = lo + tid; e < hi; e += 128) dp += __expf(raw_attn[e] - m);
#pragma unroll
  for (int o = 32; o >= 1; o >>= 1) dp += __shfl_xor(dp, o, 64);
  if (t2 == 0) sred[g] = dp;
  __syncthreads();
  const float inv = (deg > 0) ? 1.0f / (sred[0] + sred[1]) : 0.0f;

  // pass 3: chunked gather; 8 edges in flight per wave
  float accx = 0.f, accy = 0.f;
  for (int c0 = 0; c0 < deg; c0 += 128) {
    const int n = min(128, deg - c0);
    __syncthreads();
    if (tid < n) {
      int e = lo + c0 + tid;
      float ex = __expf(raw_attn[e] - m) * inv;
      raw_attn[e] = ex;  // normalized attn output (same thread read first)
      sex[tid] = ex;
      ssrc[tid] = src_idx[e];
    } else {
      sex[tid] = 0.f;
      ssrc[tid] = 0;
    }
    __syncthreads();
    const int nb = (n + 7) >> 3;
    for (int b = g; b < nb; b += 2) {
      const int base = b * 8;
#pragma unroll
      for (int j = 0; j < 8; j++) {
        float ex = sex[base + j];
        int s = ssrc[base + j];
        uint32 u = h_src_bf2[(size_t)s * 64 + t2];
        accx = fmaf(ex, bf_lo(u), accx);
        accy = fmaf(ex, bf_hi(u), accy);
      }
    }
  }
  if (g == 1) { sacc[t2][0] = accx; sacc[t2][1] = accy; }
  __syncthreads();
  if (g == 0) {
    float2 outv;
    outv.x = accx + sacc[t2][0];
    outv.y = accy + sacc[t2][1];
    *(float2*)(h_global + (size_t)v * D128 + t2 * 2) = outv;
  }
}

// ---------------------------------------------------------------------------
// out = [h_dst|h_global] @ Wo + bo; x = h_dst + out; y = LN(x)*gamma+beta
// ---------------------------------------------------------------------------
__global__ __launch_bounds__(128) void out_ln_kernel(
    const float* __restrict__ h_dst, const float* __restrict__ h_global,
    const float* __restrict__ Wo, const float* __restrict__ bo,
    const float* __restrict__ gamma, const float* __restrict__ beta,
    float* __restrict__ y, int N) {
  const int t = threadIdx.x;
  const int v0 = blockIdx.x * ROWS;
  __shared__ float xs[ROWS][260];
  __shared__ float redbuf[ROWS][2][2];

#pragma unroll
  for (int r = 0; r < ROWS; r++) {
    int v = v0 + r;
    float hd = 0.f, hg = 0.f;
    if (v < N) {
      hd = h_dst[(size_t)v * D128 + t];
      hg = h_global[(size_t)v * D128 + t];
    }
    xs[r][t] = hd;
    xs[r][128 + t] = hg;
  }
  __syncthreads();

  float o[ROWS];
#pragma unroll
  for (int r = 0; r < ROWS; r++) o[r] = bo[t];

  for (int k = 0; k < 256; k += 4) {
    float w0 = Wo[(size_t)(k + 0) * D128 + t];
    float w1 = Wo[(size_t)(k + 1) * D128 + t];
    float w2_ = Wo[(size_t)(k + 2) * D128 + t];
    float w3 = Wo[(size_t)(k + 3) * D128 + t];
#pragma unroll
    for (int r = 0; r < ROWS; r++) {
      float4 xv = *(const float4*)(&xs[r][k]);
      o[r] = fmaf(xv.x, w0, o[r]);
      o[r] = fmaf(xv.y, w1, o[r]);
      o[r] = fmaf(xv.z, w2_, o[r]);
      o[r] = fmaf(xv.w, w3, o[r]);
    }
  }

  const int lane = t & 63;
  const int wv = t >> 6;
  float xr[ROWS];
#pragma unroll
  for (int r = 0; r < ROWS; r++) {
    float x = xs[r][t] + o[r];
    xr[r] = x;
    float s1 = x, s2 = x * x;
#pragma unroll
    for (int off = 32; off >= 1; off >>= 1) {
      s1 += __shfl_xor(s1, off, 64);
      s2 += __shfl_xor(s2, off, 64);
    }
    if (lane == 0) { redbuf[r][wv][0] = s1; redbuf[r][wv][1] = s2; }
  }
  __syncthreads();

#pragma unroll
  for (int r = 0; r < ROWS; r++) {
    int v = v0 + r;
    if (v >= N) continue;
    float S1 = redbuf[r][0][0] + redbuf[r][1][0];
    float S2 = redbuf[r][0][1] + redbuf[r][1][1];
    float mu = S1 * (1.0f / 128.0f);
    float var = S2 * (1.0f / 128.0f) - mu * mu;
    float out = (xr[r] - mu) / sqrtf(var + 1e-5f) * gamma[t] + beta[t];
    y[(size_t)v * D128 + t] = out;
  }
}

extern "C" void kernel_launch(void* const* d_in, const int* in_sizes, int n_in,
                              void* d_out, int out_size, void* d_ws, size_t ws_size,
                              hipStream_t stream) {
  const float* h_src = (const float*)d_in[0];
  const float* h_dst = (const float*)d_in[1];
  const float* s_emb = (const float*)d_in[2];
  const float* ew    = (const float*)d_in[3];
  const int* src_idx = (const int*)d_in[4];
  const int* dst_idx = (const int*)d_in[5];
  const float* W1    = (const float*)d_in[6];
  const float* w2    = (const float*)d_in[7];
  const float* Wo    = (const float*)d_in[8];
  const float* bo    = (const float*)d_in[9];
  const float* gamma = (const float*)d_in[10];
  const float* beta  = (const float*)d_in[11];

  const int N_src = in_sizes[0] / D128;
  const int N_dst = in_sizes[1] / D128;
  const int E = in_sizes[3];

  float* out_y = (float*)d_out;                       // [N_dst*128]
  float* out_attn = out_y + (size_t)N_dst * D128;     // [E]

  // ws layout (uints hold 2 bf16):
  uint32* p_src_bf = (uint32*)d_ws;                         // N_src*64
  uint32* p_dst_bf = p_src_bf + (size_t)N_src * 64;         // N_dst*64
  uint32* h_src_bf = p_dst_bf + (size_t)N_dst * 64;         // N_src*64
  float* h_glob = (float*)(h_src_bf + (size_t)N_src * 64);  // N_dst*128
  int* seg_off = (int*)(h_glob + (size_t)N_dst * D128);     // N_dst+1

  seg_offsets_kernel<<<(E + 255) / 256, 256, 0, stream>>>(dst_idx, seg_off, E, N_dst);
  gemm_mfma<<<(N_src + 63) / 64, 256, 0, stream>>>(
      h_src, W1, (unsigned short*)p_src_bf, h_src_bf, N_src);
  gemm_mfma<<<(N_dst + 63) / 64, 256, 0, stream>>>(
      s_emb, W1 + D128 * D128, (unsigned short*)p_dst_bf, (uint32*)nullptr, N_dst);
  edge_raw_kernel<<<(E + 15) / 16, 256, 0, stream>>>(p_src_bf, p_dst_bf, w2, ew,
                                                     src_idx, dst_idx, out_attn, E);
  dst_agg_kernel<<<N_dst, 128, 0, stream>>>(out_attn, h_src_bf, src_idx, seg_off,
                                            h_glob);
  out_ln_kernel<<<(N_dst + ROWS - 1) / ROWS, 128, 0, stream>>>(
      h_dst, h_glob, Wo, bo, gamma, beta, out_y, N_dst);
}